// Round 12
// baseline (93.287 us; speedup 1.0000x reference)
//
#include <hip/hip_runtime.h>

// Sinkhorn on 8192 independent 64x64 f32 matrices.
// R10 structure (256-thr block = 4 waves = 2 matrices, each on a 2-wave
// pair; rotated u/v so readlane indices are literals) with the inner dot
// rewritten in inline asm:
//   32x v_readlane_b32 -> s36..s67, then 16x v_pk_fma_f32 with SGPR-PAIR
//   packed broadcasts against float2-packed K registers.
// Cuts the dot stream from 4 ops/2-terms (2 RL + 2 fma) to 3 (2 RL +
// 1 pk_fma) = -25% of the dominant VALU stream, and forces K into real
// VGPRs (asm "v" operands) instead of AGPR-parked copies.

static constexpr int   kIters = 20;
static constexpr float kEps   = 1e-6f;

__device__ __forceinline__ float RLf(float x, int l) {
    return __int_as_float(__builtin_amdgcn_readlane(__float_as_int(x), l));
}

// 32-term dot: sum_k bc[k] * K2[k/2][k%2], where bc[k] = lane k's value of
// `bc` (wave-uniform result is NOT needed; each lane accumulates with its
// own K slice). 32 readlanes into s36..s67, then 16 v_pk_fma_f32.
__device__ __forceinline__ float dot32pk(const float2* K2, float bc) {
    float2 a0 = {0.f, 0.f}, a1 = {0.f, 0.f}, a2 = {0.f, 0.f}, a3 = {0.f, 0.f};
    asm volatile(
        "v_readlane_b32 s36, %[b], 0\n\t"
        "v_readlane_b32 s37, %[b], 1\n\t"
        "v_readlane_b32 s38, %[b], 2\n\t"
        "v_readlane_b32 s39, %[b], 3\n\t"
        "v_readlane_b32 s40, %[b], 4\n\t"
        "v_readlane_b32 s41, %[b], 5\n\t"
        "v_readlane_b32 s42, %[b], 6\n\t"
        "v_readlane_b32 s43, %[b], 7\n\t"
        "v_readlane_b32 s44, %[b], 8\n\t"
        "v_readlane_b32 s45, %[b], 9\n\t"
        "v_readlane_b32 s46, %[b], 10\n\t"
        "v_readlane_b32 s47, %[b], 11\n\t"
        "v_readlane_b32 s48, %[b], 12\n\t"
        "v_readlane_b32 s49, %[b], 13\n\t"
        "v_readlane_b32 s50, %[b], 14\n\t"
        "v_readlane_b32 s51, %[b], 15\n\t"
        "v_readlane_b32 s52, %[b], 16\n\t"
        "v_readlane_b32 s53, %[b], 17\n\t"
        "v_readlane_b32 s54, %[b], 18\n\t"
        "v_readlane_b32 s55, %[b], 19\n\t"
        "v_readlane_b32 s56, %[b], 20\n\t"
        "v_readlane_b32 s57, %[b], 21\n\t"
        "v_readlane_b32 s58, %[b], 22\n\t"
        "v_readlane_b32 s59, %[b], 23\n\t"
        "v_readlane_b32 s60, %[b], 24\n\t"
        "v_readlane_b32 s61, %[b], 25\n\t"
        "v_readlane_b32 s62, %[b], 26\n\t"
        "v_readlane_b32 s63, %[b], 27\n\t"
        "v_readlane_b32 s64, %[b], 28\n\t"
        "v_readlane_b32 s65, %[b], 29\n\t"
        "v_readlane_b32 s66, %[b], 30\n\t"
        "v_readlane_b32 s67, %[b], 31\n\t"
        "v_pk_fma_f32 %[a0], s[36:37], %[k0], %[a0]\n\t"
        "v_pk_fma_f32 %[a1], s[38:39], %[k1], %[a1]\n\t"
        "v_pk_fma_f32 %[a2], s[40:41], %[k2], %[a2]\n\t"
        "v_pk_fma_f32 %[a3], s[42:43], %[k3], %[a3]\n\t"
        "v_pk_fma_f32 %[a0], s[44:45], %[k4], %[a0]\n\t"
        "v_pk_fma_f32 %[a1], s[46:47], %[k5], %[a1]\n\t"
        "v_pk_fma_f32 %[a2], s[48:49], %[k6], %[a2]\n\t"
        "v_pk_fma_f32 %[a3], s[50:51], %[k7], %[a3]\n\t"
        "v_pk_fma_f32 %[a0], s[52:53], %[k8], %[a0]\n\t"
        "v_pk_fma_f32 %[a1], s[54:55], %[k9], %[a1]\n\t"
        "v_pk_fma_f32 %[a2], s[56:57], %[k10], %[a2]\n\t"
        "v_pk_fma_f32 %[a3], s[58:59], %[k11], %[a3]\n\t"
        "v_pk_fma_f32 %[a0], s[60:61], %[k12], %[a0]\n\t"
        "v_pk_fma_f32 %[a1], s[62:63], %[k13], %[a1]\n\t"
        "v_pk_fma_f32 %[a2], s[64:65], %[k14], %[a2]\n\t"
        "v_pk_fma_f32 %[a3], s[66:67], %[k15], %[a3]\n\t"
        : [a0] "+v"(a0), [a1] "+v"(a1), [a2] "+v"(a2), [a3] "+v"(a3)
        : [b] "v"(bc),
          [k0] "v"(K2[0]),  [k1] "v"(K2[1]),  [k2] "v"(K2[2]),  [k3] "v"(K2[3]),
          [k4] "v"(K2[4]),  [k5] "v"(K2[5]),  [k6] "v"(K2[6]),  [k7] "v"(K2[7]),
          [k8] "v"(K2[8]),  [k9] "v"(K2[9]),  [k10] "v"(K2[10]), [k11] "v"(K2[11]),
          [k12] "v"(K2[12]), [k13] "v"(K2[13]), [k14] "v"(K2[14]), [k15] "v"(K2[15])
        : "s36","s37","s38","s39","s40","s41","s42","s43",
          "s44","s45","s46","s47","s48","s49","s50","s51",
          "s52","s53","s54","s55","s56","s57","s58","s59",
          "s60","s61","s62","s63","s64","s65","s66","s67");
    return ((a0.x + a0.y) + (a1.x + a1.y)) + ((a2.x + a2.y) + (a3.x + a3.y));
}

__global__ __launch_bounds__(256) void sinkhorn64_pk(const float* __restrict__ in,
                                                     float* __restrict__ out) {
    __shared__ float xb0[2][2][64];   // [matrix-pair][half][lane]
    __shared__ float xb1[2][2][64];
    const int tid  = threadIdx.x;
    const int wid  = tid >> 6;
    const int p    = wid >> 1;               // which matrix in this block
    const int h    = wid & 1;                // which half this wave owns
    const int lane = tid & 63;
    const int c    = (lane + 32 * h) & 63;   // rotated index (self-inverse)
    const long m   = (long)blockIdx.x * 2 + p;   // matrix 0..8191
    const float* __restrict__ A = in  + m * 4096;
    float* __restrict__ O       = out + m * 4096;

    // cK2[t] = (A[32h+2t][lane], A[32h+2t+1][lane])  (coalesced 256B loads)
    float2 cK2[16];
#pragma unroll
    for (int t = 0; t < 16; ++t) {
        cK2[t].x = A[((32 * h + 2 * t + 0) << 6) + lane];
        cK2[t].y = A[((32 * h + 2 * t + 1) << 6) + lane];
    }

    // rK2[t] = (A[lane][32h+2t], A[lane][32h+2t+1])  (float4 loads)
    float2 rK2[16];
#pragma unroll
    for (int k4 = 0; k4 < 8; ++k4) {
        const float4 f = *reinterpret_cast<const float4*>(A + (lane << 6) + 32 * h + (k4 << 2));
        rK2[2 * k4 + 0].x = f.x; rK2[2 * k4 + 0].y = f.y;
        rK2[2 * k4 + 1].x = f.z; rK2[2 * k4 + 1].y = f.w;
    }

    // Row max: own-half partial, exchange, combine (plain and rotated).
    float pm = fmaxf(rK2[0].x, rK2[0].y);
#pragma unroll
    for (int t = 1; t < 16; ++t) pm = fmaxf(pm, fmaxf(rK2[t].x, rK2[t].y));
    xb0[p][h][lane] = pm;
    __syncthreads();
    const float mx  = fmaxf(pm, xb0[p][1 - h][lane]);      // max of row `lane`
    const float mxr = fmaxf(xb0[p][0][c], xb0[p][1][c]);   // max of row `c`

#pragma unroll
    for (int t = 0; t < 16; ++t) {
        rK2[t].x = __expf(rK2[t].x - mx);
        rK2[t].y = __expf(rK2[t].y - mx);
        cK2[t].x = __expf(cK2[t].x - RLf(mxr, 2 * t + 0));
        cK2[t].y = __expf(cK2[t].y - RLf(mxr, 2 * t + 1));
    }

    // Rotated scaling vectors: lane holds u_c, v_c.
    float ur = 1.0f, vr = 1.0f;

#pragma unroll 1
    for (int it = 0; it < kIters; ++it) {
        // partial (K v)_{row=lane} over own columns; v[32h+k] = lane k of vr
        xb1[p][h][lane] = dot32pk(rK2, vr);
        __syncthreads();
        const float w = xb1[p][0][c] + xb1[p][1][c];          // w for row c
        ur = ur * __builtin_amdgcn_rcpf(fmaf(ur, w, kEps));

        // partial (K^T u)_{col=lane} over own rows; u[32h+i] = lane i of ur
        xb0[p][h][lane] = dot32pk(cK2, ur);
        __syncthreads();
        const float t = xb0[p][0][c] + xb0[p][1][c];          // t for col c
        vr = vr * __builtin_amdgcn_rcpf(fmaf(vr, t, kEps));
    }

    // Unrotate v: wave h=0 of this pair holds identity layout.
    xb1[p][h][lane] = vr;
    __syncthreads();
    const float vfin = xb1[p][0][lane];

    // O[32h+i][lane] = u_{32h+i} * K[32h+i][lane] * v_lane  (coalesced)
#pragma unroll
    for (int t = 0; t < 16; ++t) {
        O[((32 * h + 2 * t + 0) << 6) + lane] = RLf(ur, 2 * t + 0) * cK2[t].x * vfin;
        O[((32 * h + 2 * t + 1) << 6) + lane] = RLf(ur, 2 * t + 1) * cK2[t].y * vfin;
    }
}

extern "C" void kernel_launch(void* const* d_in, const int* in_sizes, int n_in,
                              void* d_out, int out_size, void* d_ws, size_t ws_size,
                              hipStream_t stream) {
    const float* in = (const float*)d_in[0];
    float* out      = (float*)d_out;
    // 8192 matrices, 2 matrices per 256-thread (4-wave) block.
    sinkhorn64_pk<<<4096, 256, 0, stream>>>(in, out);
}